// Round 1
// baseline (1183.326 us; speedup 1.0000x reference)
//
#include <hip/hip_runtime.h>
#include <hip/hip_bf16.h>
#include <math.h>

// Problem constants
#define LSEQ 2048
#define DMODEL 768
#define NHEAD 12
#define DHEAD 64
#define D3 2304
#define EPSLN 1e-5f

// ---------------------------------------------------------------------------
// Kernel 1: LayerNorm over last dim (768), with weight+bias. One block per row.
// ---------------------------------------------------------------------------
__global__ __launch_bounds__(256) void ln_kernel(const float* __restrict__ x,
                                                 const float* __restrict__ w,
                                                 const float* __restrict__ b,
                                                 float* __restrict__ out) {
    int row = blockIdx.x;
    const float* xr = x + (size_t)row * DMODEL;
    float* orow = out + (size_t)row * DMODEL;
    __shared__ float buf[8];

    float s = 0.f, s2 = 0.f;
    for (int i = threadIdx.x; i < DMODEL; i += 256) {
        float v = xr[i];
        s += v; s2 += v * v;
    }
    for (int o = 32; o > 0; o >>= 1) { s += __shfl_down(s, o); s2 += __shfl_down(s2, o); }
    int wid = threadIdx.x >> 6, lane = threadIdx.x & 63;
    if (lane == 0) { buf[wid] = s; buf[4 + wid] = s2; }
    __syncthreads();
    s = buf[0] + buf[1] + buf[2] + buf[3];
    s2 = buf[4] + buf[5] + buf[6] + buf[7];
    float mean = s * (1.0f / DMODEL);
    float var = s2 * (1.0f / DMODEL) - mean * mean;
    float r = rsqrtf(var + EPSLN);
    for (int i = threadIdx.x; i < DMODEL; i += 256) {
        orow[i] = (xr[i] - mean) * r * w[i] + b[i];
    }
}

// ---------------------------------------------------------------------------
// Kernel 2: generic fp32 tiled GEMM  C[M,N] = A[M,K] @ B[K,N]  (all row-major)
// BM=BN=64, BK=16, 256 threads, each thread computes 4x4.
// ---------------------------------------------------------------------------
__global__ __launch_bounds__(256) void gemm_f32(const float* __restrict__ A,
                                                const float* __restrict__ B,
                                                float* __restrict__ C,
                                                int M, int N, int K) {
    __shared__ float As[16][65];  // As[k][m]
    __shared__ float Bs[16][65];  // Bs[k][n]
    int bx = blockIdx.x;  // N tile
    int by = blockIdx.y;  // M tile
    int tid = threadIdx.x;
    int tx = tid & 15;       // n sub
    int ty = tid >> 4;       // m sub
    float acc[4][4] = {};

    for (int k0 = 0; k0 < K; k0 += 16) {
        for (int e = tid; e < 64 * 16; e += 256) {
            int r = e >> 4, c = e & 15;  // r: m in tile, c: k in tile
            As[c][r] = A[(size_t)(by * 64 + r) * K + k0 + c];
        }
        for (int e = tid; e < 16 * 64; e += 256) {
            int r = e >> 6, c = e & 63;  // r: k in tile, c: n in tile
            Bs[r][c] = B[(size_t)(k0 + r) * N + bx * 64 + c];
        }
        __syncthreads();
#pragma unroll
        for (int kk = 0; kk < 16; ++kk) {
            float a[4], b[4];
#pragma unroll
            for (int i = 0; i < 4; ++i) a[i] = As[kk][ty * 4 + i];
#pragma unroll
            for (int j = 0; j < 4; ++j) b[j] = Bs[kk][tx * 4 + j];
#pragma unroll
            for (int i = 0; i < 4; ++i)
#pragma unroll
                for (int j = 0; j < 4; ++j) acc[i][j] += a[i] * b[j];
        }
        __syncthreads();
    }
#pragma unroll
    for (int i = 0; i < 4; ++i)
#pragma unroll
        for (int j = 0; j < 4; ++j)
            C[(size_t)(by * 64 + ty * 4 + i) * N + bx * 64 + tx * 4 + j] = acc[i][j];
}

// ---------------------------------------------------------------------------
// Kernel 3: qk-LayerNorm (over full d_model, weight only) + RoPE + reorganize
// q,k,v into [H][L][DH] layout. One block per token.
// ---------------------------------------------------------------------------
__global__ __launch_bounds__(256) void qkln_rope_kernel(const float* __restrict__ qkv,
                                                        const float* __restrict__ qw,
                                                        const float* __restrict__ kw,
                                                        float* __restrict__ qh,
                                                        float* __restrict__ kh,
                                                        float* __restrict__ vh) {
    int l = blockIdx.x;
    const float* qr = qkv + (size_t)l * D3;
    const float* kr = qr + DMODEL;
    const float* vr = qr + 2 * DMODEL;
    __shared__ float buf[16];

    float sq = 0.f, sq2 = 0.f, sk = 0.f, sk2 = 0.f;
    for (int i = threadIdx.x; i < DMODEL; i += 256) {
        float a = qr[i]; sq += a; sq2 += a * a;
        float b = kr[i]; sk += b; sk2 += b * b;
    }
    for (int o = 32; o > 0; o >>= 1) {
        sq += __shfl_down(sq, o); sq2 += __shfl_down(sq2, o);
        sk += __shfl_down(sk, o); sk2 += __shfl_down(sk2, o);
    }
    int wid = threadIdx.x >> 6, lane = threadIdx.x & 63;
    if (lane == 0) { buf[wid] = sq; buf[4 + wid] = sq2; buf[8 + wid] = sk; buf[12 + wid] = sk2; }
    __syncthreads();
    sq = buf[0] + buf[1] + buf[2] + buf[3];
    sq2 = buf[4] + buf[5] + buf[6] + buf[7];
    sk = buf[8] + buf[9] + buf[10] + buf[11];
    sk2 = buf[12] + buf[13] + buf[14] + buf[15];
    float mq = sq * (1.0f / DMODEL);
    float vq = sq2 * (1.0f / DMODEL) - mq * mq;
    float rq = rsqrtf(vq + EPSLN);
    float mk = sk * (1.0f / DMODEL);
    float vk = sk2 * (1.0f / DMODEL) - mk * mk;
    float rk = rsqrtf(vk + EPSLN);

    // RoPE pairs: 12 heads * 32 pairs = 384 work items
    const float LN10000 = 9.210340371976184f;
    for (int p = threadIdx.x; p < NHEAD * 32; p += 256) {
        int h = p >> 5, j = p & 31;
        int i1 = h * DHEAD + j;
        int i2 = i1 + 32;
        float q1 = (qr[i1] - mq) * rq * qw[i1];
        float q2 = (qr[i2] - mq) * rq * qw[i2];
        float k1 = (kr[i1] - mk) * rk * kw[i1];
        float k2 = (kr[i2] - mk) * rk * kw[i2];
        float inv = expf(-LN10000 * (float)(2 * j) * (1.0f / DHEAD));
        float ang = (float)l * inv;
        float c, s;
        sincosf(ang, &s, &c);
        size_t base = ((size_t)h * LSEQ + l) * DHEAD;
        qh[base + j]      = q1 * c - q2 * s;
        qh[base + 32 + j] = q2 * c + q1 * s;
        kh[base + j]      = k1 * c - k2 * s;
        kh[base + 32 + j] = k2 * c + k1 * s;
    }
    // V: plain reorganize
    for (int i = threadIdx.x; i < DMODEL; i += 256) {
        int h = i >> 6, d = i & 63;
        vh[((size_t)h * LSEQ + l) * DHEAD + d] = vr[i];
    }
}

// ---------------------------------------------------------------------------
// Kernel 4: attention for 4 query rows of one head per block.
// scores kept in LDS (full row, fp32), additive 0/1 same-doc bias, softmax, PV.
// ctx written as [L][D] (token-major) for the out-proj GEMM.
// ---------------------------------------------------------------------------
#define QR 4
#define KT 64
__global__ __launch_bounds__(256) void attn_kernel(const float* __restrict__ qh,
                                                   const float* __restrict__ kh,
                                                   const float* __restrict__ vh,
                                                   const int* __restrict__ seq,
                                                   float* __restrict__ ctx) {
    int h = blockIdx.y;
    int q0 = blockIdx.x * QR;
    int tid = threadIdx.x;
    int r = tid >> 6;      // query sub-row 0..3 (one wave per row)
    int kk = tid & 63;     // k index within tile / head dim in PV

    __shared__ float sc[QR][LSEQ];     // 32 KB score rows
    __shared__ float kt[KT][DHEAD + 1];  // 16.25 KB staging tile (K then V)
    __shared__ float red[8];
    __shared__ float rowinv[QR];

    // q row into registers (wave-broadcast reads)
    float qreg[DHEAD];
    const float* qp = qh + ((size_t)h * LSEQ + q0 + r) * DHEAD;
#pragma unroll
    for (int d = 0; d < DHEAD; ++d) qreg[d] = qp[d];
    int sqr = seq[q0 + r];

    // Phase 1: scores
    for (int t = 0; t < LSEQ / KT; ++t) {
        __syncthreads();
        for (int e = tid; e < KT * DHEAD; e += 256) {
            int rr = e >> 6, cc = e & 63;
            kt[rr][cc] = kh[((size_t)h * LSEQ + t * KT + rr) * DHEAD + cc];
        }
        __syncthreads();
        float acc = 0.f;
#pragma unroll
        for (int d = 0; d < DHEAD; ++d) acc += qreg[d] * kt[kk][d];
        int kidx = t * KT + kk;
        float bias = (seq[kidx] == sqr) ? 1.0f : 0.0f;
        sc[r][kidx] = acc * 0.125f + bias;
    }
    __syncthreads();

    // Phase 2: softmax per row (all 256 threads cooperate per row)
    for (int rr = 0; rr < QR; ++rr) {
        float m = -1e30f;
        for (int i = tid; i < LSEQ; i += 256) m = fmaxf(m, sc[rr][i]);
        for (int o = 32; o > 0; o >>= 1) m = fmaxf(m, __shfl_down(m, o));
        __syncthreads();
        if ((tid & 63) == 0) red[tid >> 6] = m;
        __syncthreads();
        m = fmaxf(fmaxf(red[0], red[1]), fmaxf(red[2], red[3]));

        float s = 0.f;
        for (int i = tid; i < LSEQ; i += 256) {
            float p = expf(sc[rr][i] - m);
            sc[rr][i] = p;
            s += p;
        }
        for (int o = 32; o > 0; o >>= 1) s += __shfl_down(s, o);
        __syncthreads();
        if ((tid & 63) == 0) red[tid >> 6] = s;
        __syncthreads();
        s = red[0] + red[1] + red[2] + red[3];
        if (tid == 0) rowinv[rr] = 1.0f / s;
    }
    __syncthreads();

    // Phase 3: PV. thread owns (r, d=kk)
    float oacc = 0.f;
    for (int t = 0; t < LSEQ / KT; ++t) {
        __syncthreads();
        for (int e = tid; e < KT * DHEAD; e += 256) {
            int rr = e >> 6, cc = e & 63;
            kt[rr][cc] = vh[((size_t)h * LSEQ + t * KT + rr) * DHEAD + cc];
        }
        __syncthreads();
#pragma unroll
        for (int j = 0; j < KT; ++j) oacc += sc[r][t * KT + j] * kt[j][kk];
    }
    ctx[(size_t)(q0 + r) * DMODEL + h * DHEAD + kk] = oacc * rowinv[r];
}

// ---------------------------------------------------------------------------
// Launch
// ---------------------------------------------------------------------------
extern "C" void kernel_launch(void* const* d_in, const int* in_sizes, int n_in,
                              void* d_out, int out_size, void* d_ws, size_t ws_size,
                              hipStream_t stream) {
    const float* x      = (const float*)d_in[0];
    // d_in[1] attention_mask: all-true, additive bias contribution handled via seq_id only
    const int*   seq    = (const int*)d_in[2];
    const float* ln_w   = (const float*)d_in[3];
    const float* ln_b   = (const float*)d_in[4];
    const float* w_qkv  = (const float*)d_in[5];
    const float* q_ln_w = (const float*)d_in[6];
    const float* k_ln_w = (const float*)d_in[7];
    const float* w_out  = (const float*)d_in[8];
    float* out = (float*)d_out;

    float* ws = (float*)d_ws;
    const size_t LD = (size_t)LSEQ * DMODEL;          // 1,572,864
    float* h   = ws;                                   // [L, D]
    float* qkv = ws + LD;                              // [L, 3D]
    float* qh  = ws + LD + (size_t)LSEQ * D3;          // [H][L][DH]
    float* kh  = qh + LD;
    float* vh  = kh + LD;
    float* ctx = h;  // h is dead after qkv GEMM; reuse for ctx [L, D]

    hipLaunchKernelGGL(ln_kernel, dim3(LSEQ), dim3(256), 0, stream, x, ln_w, ln_b, h);
    hipLaunchKernelGGL(gemm_f32, dim3(D3 / 64, LSEQ / 64), dim3(256), 0, stream,
                       h, w_qkv, qkv, LSEQ, D3, DMODEL);
    hipLaunchKernelGGL(qkln_rope_kernel, dim3(LSEQ), dim3(256), 0, stream,
                       qkv, q_ln_w, k_ln_w, qh, kh, vh);
    hipLaunchKernelGGL(attn_kernel, dim3(LSEQ / QR, NHEAD), dim3(256), 0, stream,
                       qh, kh, vh, seq, ctx);
    hipLaunchKernelGGL(gemm_f32, dim3(DMODEL / 64, LSEQ / 64), dim3(256), 0, stream,
                       ctx, w_out, out, LSEQ, DMODEL, DMODEL);
}

// Round 7
// 406.193 us; speedup vs baseline: 2.9132x; 2.9132x over previous
//
#include <hip/hip_runtime.h>
#include <hip/hip_bf16.h>
#include <math.h>

// Problem constants
#define LSEQ 2048
#define DMODEL 768
#define NHEAD 12
#define DHEAD 64
#define D3 2304
#define EPSLN 1e-5f

typedef __attribute__((ext_vector_type(8))) short short8;
typedef __attribute__((ext_vector_type(4))) float f32x4;

static __device__ __forceinline__ unsigned short f2bf(float x) {
    __hip_bfloat16 b = __float2bfloat16(x);
    return *reinterpret_cast<unsigned short*>(&b);
}

// ---------------------------------------------------------------------------
// Kernel 1: LayerNorm over last dim (768), with weight+bias. One block per row.
// ---------------------------------------------------------------------------
__global__ __launch_bounds__(256) void ln_kernel(const float* __restrict__ x,
                                                 const float* __restrict__ w,
                                                 const float* __restrict__ b,
                                                 float* __restrict__ out) {
    int row = blockIdx.x;
    const float* xr = x + (size_t)row * DMODEL;
    float* orow = out + (size_t)row * DMODEL;
    __shared__ float buf[8];

    float s = 0.f, s2 = 0.f;
    for (int i = threadIdx.x; i < DMODEL; i += 256) {
        float v = xr[i];
        s += v; s2 += v * v;
    }
    for (int o = 32; o > 0; o >>= 1) { s += __shfl_down(s, o); s2 += __shfl_down(s2, o); }
    int wid = threadIdx.x >> 6, lane = threadIdx.x & 63;
    if (lane == 0) { buf[wid] = s; buf[4 + wid] = s2; }
    __syncthreads();
    s = buf[0] + buf[1] + buf[2] + buf[3];
    s2 = buf[4] + buf[5] + buf[6] + buf[7];
    float mean = s * (1.0f / DMODEL);
    float var = s2 * (1.0f / DMODEL) - mean * mean;
    float r = rsqrtf(var + EPSLN);
    for (int i = threadIdx.x; i < DMODEL; i += 256) {
        orow[i] = (xr[i] - mean) * r * w[i] + b[i];
    }
}

// ---------------------------------------------------------------------------
// Kernel 2: generic fp32 tiled GEMM  C[M,N] = A[M,K] @ B[K,N]  (all row-major)
// ---------------------------------------------------------------------------
__global__ __launch_bounds__(256) void gemm_f32(const float* __restrict__ A,
                                                const float* __restrict__ B,
                                                float* __restrict__ C,
                                                int M, int N, int K) {
    __shared__ float As[16][65];
    __shared__ float Bs[16][65];
    int bx = blockIdx.x;
    int by = blockIdx.y;
    int tid = threadIdx.x;
    int tx = tid & 15;
    int ty = tid >> 4;
    float acc[4][4] = {};

    for (int k0 = 0; k0 < K; k0 += 16) {
        for (int e = tid; e < 64 * 16; e += 256) {
            int r = e >> 4, c = e & 15;
            As[c][r] = A[(size_t)(by * 64 + r) * K + k0 + c];
        }
        for (int e = tid; e < 16 * 64; e += 256) {
            int r = e >> 6, c = e & 63;
            Bs[r][c] = B[(size_t)(k0 + r) * N + bx * 64 + c];
        }
        __syncthreads();
#pragma unroll
        for (int kk = 0; kk < 16; ++kk) {
            float a[4], b[4];
#pragma unroll
            for (int i = 0; i < 4; ++i) a[i] = As[kk][ty * 4 + i];
#pragma unroll
            for (int j = 0; j < 4; ++j) b[j] = Bs[kk][tx * 4 + j];
#pragma unroll
            for (int i = 0; i < 4; ++i)
#pragma unroll
                for (int j = 0; j < 4; ++j) acc[i][j] += a[i] * b[j];
        }
        __syncthreads();
    }
#pragma unroll
    for (int i = 0; i < 4; ++i)
#pragma unroll
        for (int j = 0; j < 4; ++j)
            C[(size_t)(by * 64 + ty * 4 + i) * N + bx * 64 + tx * 4 + j] = acc[i][j];
}

// ---------------------------------------------------------------------------
// Kernel 3: qk-LayerNorm (full d_model, weight only) + RoPE -> bf16 q,k in
// [H][L][DH] layout. One block per token. (V handled by v_transpose.)
// ---------------------------------------------------------------------------
__global__ __launch_bounds__(256) void qkln_rope_kernel(const float* __restrict__ qkv,
                                                        const float* __restrict__ qw,
                                                        const float* __restrict__ kw,
                                                        __hip_bfloat16* __restrict__ qh,
                                                        __hip_bfloat16* __restrict__ kh) {
    int l = blockIdx.x;
    const float* qr = qkv + (size_t)l * D3;
    const float* kr = qr + DMODEL;
    __shared__ float buf[16];

    float sq = 0.f, sq2 = 0.f, sk = 0.f, sk2 = 0.f;
    for (int i = threadIdx.x; i < DMODEL; i += 256) {
        float a = qr[i]; sq += a; sq2 += a * a;
        float b = kr[i]; sk += b; sk2 += b * b;
    }
    for (int o = 32; o > 0; o >>= 1) {
        sq += __shfl_down(sq, o); sq2 += __shfl_down(sq2, o);
        sk += __shfl_down(sk, o); sk2 += __shfl_down(sk2, o);
    }
    int wid = threadIdx.x >> 6, lane = threadIdx.x & 63;
    if (lane == 0) { buf[wid] = sq; buf[4 + wid] = sq2; buf[8 + wid] = sk; buf[12 + wid] = sk2; }
    __syncthreads();
    sq = buf[0] + buf[1] + buf[2] + buf[3];
    sq2 = buf[4] + buf[5] + buf[6] + buf[7];
    sk = buf[8] + buf[9] + buf[10] + buf[11];
    sk2 = buf[12] + buf[13] + buf[14] + buf[15];
    float mq = sq * (1.0f / DMODEL);
    float vq = sq2 * (1.0f / DMODEL) - mq * mq;
    float rq = rsqrtf(vq + EPSLN);
    float mk = sk * (1.0f / DMODEL);
    float vk = sk2 * (1.0f / DMODEL) - mk * mk;
    float rk = rsqrtf(vk + EPSLN);

    const float LN10000 = 9.210340371976184f;
    for (int p = threadIdx.x; p < NHEAD * 32; p += 256) {
        int h = p >> 5, j = p & 31;
        int i1 = h * DHEAD + j;
        int i2 = i1 + 32;
        float q1 = (qr[i1] - mq) * rq * qw[i1];
        float q2 = (qr[i2] - mq) * rq * qw[i2];
        float k1 = (kr[i1] - mk) * rk * kw[i1];
        float k2 = (kr[i2] - mk) * rk * kw[i2];
        float inv = __expf(-LN10000 * (float)(2 * j) * (1.0f / DHEAD));
        float ang = (float)l * inv;
        float c, s;
        __sincosf(ang, &s, &c);
        size_t base = ((size_t)h * LSEQ + l) * DHEAD;
        qh[base + j]      = __float2bfloat16(q1 * c - q2 * s);
        qh[base + 32 + j] = __float2bfloat16(q2 * c + q1 * s);
        kh[base + j]      = __float2bfloat16(k1 * c - k2 * s);
        kh[base + 32 + j] = __float2bfloat16(k2 * c + k1 * s);
    }
}

// ---------------------------------------------------------------------------
// Kernel 3b: V transpose -> bf16 vt[H][DH][L] (d-major) so PV B-fragments are
// contiguous along the token (K) dimension.
// ---------------------------------------------------------------------------
__global__ __launch_bounds__(256) void v_transpose(const float* __restrict__ qkv,
                                                   __hip_bfloat16* __restrict__ vt) {
    int t = blockIdx.x, h = blockIdx.y;
    int tid = threadIdx.x;
    __shared__ float tile[64][65];
    for (int e = tid; e < 4096; e += 256) {
        int tok = e >> 6, d = e & 63;
        tile[tok][d] = qkv[(size_t)(t * 64 + tok) * D3 + 2 * DMODEL + h * DHEAD + d];
    }
    __syncthreads();
    for (int e = tid; e < 4096; e += 256) {
        int d = e >> 6, tok = e & 63;
        vt[((size_t)h * DHEAD + d) * LSEQ + t * 64 + tok] = __float2bfloat16(tile[tok][d]);
    }
}

// ---------------------------------------------------------------------------
// Kernel 4: MFMA flash attention. Block = (64 q-rows, 1 head), 4 waves x 16 rows.
// K-tiles of 64 tokens. bf16 MFMA 16x16x32, fp32 accum, online softmax.
// LDS tiles are XOR-swizzled (elem ^= (row&7)<<3) with pre-swizzled global
// source addresses feeding global_load_lds (linear dest), per rule #21.
// ---------------------------------------------------------------------------
__global__ __launch_bounds__(256) void attn_mfma(const __hip_bfloat16* __restrict__ qh,
                                                 const __hip_bfloat16* __restrict__ kh,
                                                 const __hip_bfloat16* __restrict__ vt,
                                                 const int* __restrict__ seq,
                                                 float* __restrict__ ctx) {
    int h = blockIdx.y;
    int q0 = blockIdx.x * 64;
    int tid = threadIdx.x;
    int w = tid >> 6, lane = tid & 63;
    int g = lane >> 4, l16 = lane & 15;

    __shared__ __align__(16) unsigned short Klds[64 * 64];      // [tok][d]  swizzled
    __shared__ __align__(16) unsigned short Vlds[64 * 64];      // [d][tok]  swizzled
    __shared__ __align__(16) unsigned short Plds[4][16 * 64];   // per wave [qrow][tok] swizzled
    __shared__ int seq_lds[64];

    // Q fragments (A-layout: row = lane&15, k = (lane>>4)*8 + j)
    int qrow = q0 + w * 16 + l16;
    short8 qfrag[2];
    {
        const short8* qp = (const short8*)(qh + ((size_t)h * LSEQ + qrow) * DHEAD);
        qfrag[0] = qp[g];
        qfrag[1] = qp[4 + g];
    }
    int seq_q[4];
#pragma unroll
    for (int r = 0; r < 4; ++r) seq_q[r] = seq[q0 + w * 16 + g * 4 + r];

    f32x4 O[4] = {};
    float mrow[4], lrow[4];
#pragma unroll
    for (int r = 0; r < 4; ++r) { mrow[r] = -1e30f; lrow[r] = 0.f; }

    for (int t = 0; t < LSEQ / 64; ++t) {
        __syncthreads();
        // ---- stage K and V tiles (global_load_lds, 16B/lane, linear dest,
        //      swizzle applied on the per-lane GLOBAL source address) ----
#pragma unroll
        for (int i = 0; i < 2; ++i) {
            int c = 2 * w + i;
            int s = c * 64 + lane;          // slot 0..511
            int tok = s >> 3, d0 = (s & 7) * 8;
            const __hip_bfloat16* ksrc =
                kh + ((size_t)h * LSEQ + t * 64 + tok) * DHEAD + (d0 ^ ((tok & 7) << 3));
            __builtin_amdgcn_global_load_lds(
                (const __attribute__((address_space(1))) unsigned int*)ksrc,
                (__attribute__((address_space(3))) unsigned int*)&Klds[c * 512],
                16, 0, 0);
            int d = s >> 3, u0 = (s & 7) * 8;
            const __hip_bfloat16* vsrc =
                vt + ((size_t)h * DHEAD + d) * LSEQ + t * 64 + (u0 ^ ((d & 7) << 3));
            __builtin_amdgcn_global_load_lds(
                (const __attribute__((address_space(1))) unsigned int*)vsrc,
                (__attribute__((address_space(3))) unsigned int*)&Vlds[c * 512],
                16, 0, 0);
        }
        if (tid < 64) seq_lds[tid] = seq[t * 64 + tid];
        __syncthreads();

        // ---- QK^T: S[16q x 64tok] per wave ----
        f32x4 S[4];
#pragma unroll
        for (int nt = 0; nt < 4; ++nt) {
            int tok = nt * 16 + l16;
            short8 b0 = *(const short8*)&Klds[tok * 64 + ((g * 8) ^ ((tok & 7) << 3))];
            short8 b1 = *(const short8*)&Klds[tok * 64 + ((32 + g * 8) ^ ((tok & 7) << 3))];
            f32x4 acc = {0.f, 0.f, 0.f, 0.f};
            acc = __builtin_amdgcn_mfma_f32_16x16x32_bf16(qfrag[0], b0, acc, 0, 0, 0);
            acc = __builtin_amdgcn_mfma_f32_16x16x32_bf16(qfrag[1], b1, acc, 0, 0, 0);
            S[nt] = acc;
        }

        // ---- bias + online softmax (C layout: row=g*4+reg, col=nt*16+l16) ----
        int sk[4];
#pragma unroll
        for (int nt = 0; nt < 4; ++nt) sk[nt] = seq_lds[nt * 16 + l16];

        float p[4][4];
        float tmax[4];
#pragma unroll
        for (int r = 0; r < 4; ++r) tmax[r] = -1e30f;
#pragma unroll
        for (int nt = 0; nt < 4; ++nt)
#pragma unroll
            for (int r = 0; r < 4; ++r) {
                float sv = S[nt][r] * 0.125f + ((sk[nt] == seq_q[r]) ? 1.0f : 0.0f);
                p[nt][r] = sv;
                tmax[r] = fmaxf(tmax[r], sv);
            }
#pragma unroll
        for (int o = 1; o < 16; o <<= 1)
#pragma unroll
            for (int r = 0; r < 4; ++r) tmax[r] = fmaxf(tmax[r], __shfl_xor(tmax[r], o, 64));

        float rsum[4];
#pragma unroll
        for (int r = 0; r < 4; ++r) {
            float mnew = fmaxf(mrow[r], tmax[r]);
            float sc = __expf(mrow[r] - mnew);
            mrow[r] = mnew;
            lrow[r] *= sc;
#pragma unroll
            for (int nt = 0; nt < 4; ++nt) O[nt][r] *= sc;
            float rs = 0.f;
#pragma unroll
            for (int nt = 0; nt < 4; ++nt) {
                float pv = __expf(p[nt][r] - mnew);
                p[nt][r] = pv;
                rs += pv;
            }
            rsum[r] = rs;
        }
#pragma unroll
        for (int o = 1; o < 16; o <<= 1)
#pragma unroll
            for (int r = 0; r < 4; ++r) rsum[r] += __shfl_xor(rsum[r], o, 64);
#pragma unroll
        for (int r = 0; r < 4; ++r) lrow[r] += rsum[r];

        // ---- P -> LDS (bf16, swizzled). Same-wave producer/consumer. ----
        unsigned short* Pw = (unsigned short*)Plds[w];
#pragma unroll
        for (int nt = 0; nt < 4; ++nt)
#pragma unroll
            for (int r = 0; r < 4; ++r) {
                int row = g * 4 + r;
                int col = nt * 16 + l16;
                Pw[row * 64 + (col ^ ((row & 7) << 3))] = f2bf(p[nt][r]);
            }

        // ---- PV: O[16q x 64d] += P[16x64] * V[64tok x 64d] ----
#pragma unroll
        for (int nt = 0; nt < 4; ++nt) {
            int d = nt * 16 + l16;
            short8 vb0 = *(const short8*)&Vlds[d * 64 + ((g * 8) ^ ((d & 7) << 3))];
            short8 vb1 = *(const short8*)&Vlds[d * 64 + ((32 + g * 8) ^ ((d & 7) << 3))];
            int pr = l16;
            short8 pa0 = *(const short8*)&Pw[pr * 64 + ((g * 8) ^ ((pr & 7) << 3))];
            short8 pa1 = *(const short8*)&Pw[pr * 64 + ((32 + g * 8) ^ ((pr & 7) << 3))];
            O[nt] = __builtin_amdgcn_mfma_f32_16x16x32_bf16(pa0, vb0, O[nt], 0, 0, 0);
            O[nt] = __builtin_amdgcn_mfma_f32_16x16x32_bf16(pa1, vb1, O[nt], 0, 0, 0);
        }
    }

    // ---- epilogue: normalize and write ctx [L][D] ----
#pragma unroll
    for (int nt = 0; nt < 4; ++nt)
#pragma unroll
        for (int r = 0; r < 4; ++r) {
            int row = g * 4 + r;
            ctx[(size_t)(q0 + w * 16 + row) * DMODEL + h * DHEAD + nt * 16 + l16] =
                O[nt][r] / lrow[r];
        }
}

// ---------------------------------------------------------------------------
// Launch
// ---------------------------------------------------------------------------
extern "C" void kernel_launch(void* const* d_in, const int* in_sizes, int n_in,
                              void* d_out, int out_size, void* d_ws, size_t ws_size,
                              hipStream_t stream) {
    const float* x      = (const float*)d_in[0];
    const int*   seq    = (const int*)d_in[2];
    const float* ln_w   = (const float*)d_in[3];
    const float* ln_b   = (const float*)d_in[4];
    const float* w_qkv  = (const float*)d_in[5];
    const float* q_ln_w = (const float*)d_in[6];
    const float* k_ln_w = (const float*)d_in[7];
    const float* w_out  = (const float*)d_in[8];
    float* out = (float*)d_out;

    float* ws = (float*)d_ws;
    const size_t LD = (size_t)LSEQ * DMODEL;
    float* h   = ws;                              // [L, D] fp32
    float* qkv = ws + LD;                         // [L, 3D] fp32
    __hip_bfloat16* qh = (__hip_bfloat16*)(qkv + (size_t)LSEQ * D3);  // [H][L][DH]
    __hip_bfloat16* kh = qh + (size_t)NHEAD * LSEQ * DHEAD;           // [H][L][DH]
    __hip_bfloat16* vt = kh + (size_t)NHEAD * LSEQ * DHEAD;           // [H][DH][L]
    float* ctx = h;  // h is dead after qkv GEMM; reuse for ctx [L, D]

    hipLaunchKernelGGL(ln_kernel, dim3(LSEQ), dim3(256), 0, stream, x, ln_w, ln_b, h);
    hipLaunchKernelGGL(gemm_f32, dim3(D3 / 64, LSEQ / 64), dim3(256), 0, stream,
                       h, w_qkv, qkv, LSEQ, D3, DMODEL);
    hipLaunchKernelGGL(qkln_rope_kernel, dim3(LSEQ), dim3(256), 0, stream,
                       qkv, q_ln_w, k_ln_w, qh, kh);
    hipLaunchKernelGGL(v_transpose, dim3(LSEQ / 64, NHEAD), dim3(256), 0, stream,
                       qkv, vt);
    hipLaunchKernelGGL(attn_mfma, dim3(LSEQ / 64, NHEAD), dim3(256), 0, stream,
                       qh, kh, vt, seq, ctx);
    hipLaunchKernelGGL(gemm_f32, dim3(DMODEL / 64, LSEQ / 64), dim3(256), 0, stream,
                       ctx, w_out, out, LSEQ, DMODEL, DMODEL);
}

// Round 8
// 165.721 us; speedup vs baseline: 7.1405x; 2.4511x over previous
//
#include <hip/hip_runtime.h>
#include <hip/hip_bf16.h>
#include <math.h>

// Problem constants
#define LSEQ 2048
#define DMODEL 768
#define NHEAD 12
#define DHEAD 64
#define D3 2304
#define EPSLN 1e-5f

typedef __attribute__((ext_vector_type(8))) short short8;
typedef __attribute__((ext_vector_type(4))) float f32x4;

static __device__ __forceinline__ unsigned short f2bf(float x) {
    __hip_bfloat16 b = __float2bfloat16(x);
    return *reinterpret_cast<unsigned short*>(&b);
}
static __device__ __forceinline__ float bf2f(unsigned short u) {
    __hip_bfloat16 b = *reinterpret_cast<__hip_bfloat16*>(&u);
    return __bfloat162float(b);
}

// ---------------------------------------------------------------------------
// Kernel 1: LayerNorm + Dekker split -> h_hi, h_lo (bf16). One block per row.
// ---------------------------------------------------------------------------
__global__ __launch_bounds__(256) void ln_split_kernel(const float* __restrict__ x,
                                                       const float* __restrict__ w,
                                                       const float* __restrict__ b,
                                                       unsigned short* __restrict__ hhi,
                                                       unsigned short* __restrict__ hlo) {
    int row = blockIdx.x;
    const float* xr = x + (size_t)row * DMODEL;
    __shared__ float buf[8];

    float s = 0.f, s2 = 0.f;
    for (int i = threadIdx.x; i < DMODEL; i += 256) {
        float v = xr[i];
        s += v; s2 += v * v;
    }
    for (int o = 32; o > 0; o >>= 1) { s += __shfl_down(s, o); s2 += __shfl_down(s2, o); }
    int wid = threadIdx.x >> 6, lane = threadIdx.x & 63;
    if (lane == 0) { buf[wid] = s; buf[4 + wid] = s2; }
    __syncthreads();
    s = buf[0] + buf[1] + buf[2] + buf[3];
    s2 = buf[4] + buf[5] + buf[6] + buf[7];
    float mean = s * (1.0f / DMODEL);
    float var = s2 * (1.0f / DMODEL) - mean * mean;
    float r = rsqrtf(var + EPSLN);
    for (int i = threadIdx.x; i < DMODEL; i += 256) {
        float y = (xr[i] - mean) * r * w[i] + b[i];
        unsigned short hi = f2bf(y);
        hhi[(size_t)row * DMODEL + i] = hi;
        hlo[(size_t)row * DMODEL + i] = f2bf(y - bf2f(hi));
    }
}

// ---------------------------------------------------------------------------
// Kernel 1b: transpose + Dekker split: W[K][N] -> T_hi/T_lo [N][K] (bf16).
// grid (N/64, K/64), 256 threads.
// ---------------------------------------------------------------------------
__global__ __launch_bounds__(256) void transpose_split(const float* __restrict__ W,
                                                       unsigned short* __restrict__ Thi,
                                                       unsigned short* __restrict__ Tlo,
                                                       int K, int N) {
    int n0 = blockIdx.x * 64, k0 = blockIdx.y * 64;
    int tid = threadIdx.x;
    __shared__ float tile[64][65];
    for (int e = tid; e < 4096; e += 256) {
        int r = e >> 6, c = e & 63;   // r: k, c: n
        tile[r][c] = W[(size_t)(k0 + r) * N + n0 + c];
    }
    __syncthreads();
    for (int e = tid; e < 4096; e += 256) {
        int r = e >> 6, c = e & 63;   // r: n, c: k
        float v = tile[c][r];
        unsigned short hi = f2bf(v);
        size_t idx = (size_t)(n0 + r) * K + k0 + c;
        Thi[idx] = hi;
        Tlo[idx] = f2bf(v - bf2f(hi));
    }
}

// ---------------------------------------------------------------------------
// Kernel 2: split-bf16 MFMA GEMM.  C[M,N] fp32 = (Ahi+Alo) @ (Bhi+Blo)^T
// A* [M][K] bf16, B* [N][K] bf16 (pre-transposed so both operands are
// contiguous along K). 128x128 tile, BK=64, 4 waves (2x2), each 64x64 out.
// 3 MFMAs per fragment pair (hi*hi + hi*lo + lo*hi); lo*lo dropped (~eps^2).
// LDS tiles staged via global_load_lds with pre-swizzled source (rule #21),
// read with s^(row&7) 16B-slot swizzle -> 2-way (free) bank aliasing.
// ---------------------------------------------------------------------------
__global__ __launch_bounds__(256) void gemm_split(const unsigned short* __restrict__ Ahi,
                                                  const unsigned short* __restrict__ Alo,
                                                  const unsigned short* __restrict__ Bhi,
                                                  const unsigned short* __restrict__ Blo,
                                                  float* __restrict__ C,
                                                  int M, int N, int K) {
    __shared__ __align__(16) unsigned short Ah[128 * 64];
    __shared__ __align__(16) unsigned short Al[128 * 64];
    __shared__ __align__(16) unsigned short Bh[128 * 64];
    __shared__ __align__(16) unsigned short Bl[128 * 64];

    int bx = blockIdx.x, by = blockIdx.y;
    int tid = threadIdx.x;
    int w = tid >> 6, lane = tid & 63;
    int g = lane >> 4, l16 = lane & 15;
    int wm = w >> 1, wn = w & 1;      // 2x2 wave grid; wave owns 64x64

    f32x4 acc[4][4] = {};

    for (int k0 = 0; k0 < K; k0 += 64) {
        __syncthreads();
        // ---- stage 4 tiles of 128 rows x 64 bf16 (16KB each) ----
#pragma unroll
        for (int c = 0; c < 4; ++c) {
            int slotb = c * 256 + w * 64;        // wave-uniform base slot
            int slot = slotb + lane;
            int row = slot >> 3;
            int ss = (slot & 7) ^ (row & 7);     // inverse swizzle on source
            size_t offA = (size_t)(by * 128 + row) * K + k0 + ss * 8;
            size_t offB = (size_t)(bx * 128 + row) * K + k0 + ss * 8;
            __builtin_amdgcn_global_load_lds(
                (const __attribute__((address_space(1))) unsigned int*)(Ahi + offA),
                (__attribute__((address_space(3))) unsigned int*)&Ah[(size_t)slotb * 8], 16, 0, 0);
            __builtin_amdgcn_global_load_lds(
                (const __attribute__((address_space(1))) unsigned int*)(Alo + offA),
                (__attribute__((address_space(3))) unsigned int*)&Al[(size_t)slotb * 8], 16, 0, 0);
            __builtin_amdgcn_global_load_lds(
                (const __attribute__((address_space(1))) unsigned int*)(Bhi + offB),
                (__attribute__((address_space(3))) unsigned int*)&Bh[(size_t)slotb * 8], 16, 0, 0);
            __builtin_amdgcn_global_load_lds(
                (const __attribute__((address_space(1))) unsigned int*)(Blo + offB),
                (__attribute__((address_space(3))) unsigned int*)&Bl[(size_t)slotb * 8], 16, 0, 0);
        }
        __syncthreads();

        // ---- compute: 2 k-halves of 32 ----
#pragma unroll
        for (int kk = 0; kk < 2; ++kk) {
            short8 a_h[4], a_l[4], b_h[4], b_l[4];
#pragma unroll
            for (int i = 0; i < 4; ++i) {
                int row = wm * 64 + i * 16 + l16;
                int s = (kk * 4 + g) ^ (row & 7);
                a_h[i] = *(const short8*)&Ah[row * 64 + s * 8];
                a_l[i] = *(const short8*)&Al[row * 64 + s * 8];
            }
#pragma unroll
            for (int j = 0; j < 4; ++j) {
                int row = wn * 64 + j * 16 + l16;
                int s = (kk * 4 + g) ^ (row & 7);
                b_h[j] = *(const short8*)&Bh[row * 64 + s * 8];
                b_l[j] = *(const short8*)&Bl[row * 64 + s * 8];
            }
#pragma unroll
            for (int i = 0; i < 4; ++i)
#pragma unroll
                for (int j = 0; j < 4; ++j) {
                    acc[i][j] = __builtin_amdgcn_mfma_f32_16x16x32_bf16(a_h[i], b_h[j], acc[i][j], 0, 0, 0);
                    acc[i][j] = __builtin_amdgcn_mfma_f32_16x16x32_bf16(a_h[i], b_l[j], acc[i][j], 0, 0, 0);
                    acc[i][j] = __builtin_amdgcn_mfma_f32_16x16x32_bf16(a_l[i], b_h[j], acc[i][j], 0, 0, 0);
                }
        }
    }

    // ---- epilogue: C/D layout col=l16, row=g*4+r ----
#pragma unroll
    for (int i = 0; i < 4; ++i)
#pragma unroll
        for (int j = 0; j < 4; ++j)
#pragma unroll
            for (int r = 0; r < 4; ++r) {
                int m = by * 128 + wm * 64 + i * 16 + g * 4 + r;
                int n = bx * 128 + wn * 64 + j * 16 + l16;
                C[(size_t)m * N + n] = acc[i][j][r];
            }
}

// ---------------------------------------------------------------------------
// Kernel 3: qk-LayerNorm (full d_model, weight only) + RoPE -> bf16 q,k in
// [H][L][DH] layout. One block per token.
// ---------------------------------------------------------------------------
__global__ __launch_bounds__(256) void qkln_rope_kernel(const float* __restrict__ qkv,
                                                        const float* __restrict__ qw,
                                                        const float* __restrict__ kw,
                                                        __hip_bfloat16* __restrict__ qh,
                                                        __hip_bfloat16* __restrict__ kh) {
    int l = blockIdx.x;
    const float* qr = qkv + (size_t)l * D3;
    const float* kr = qr + DMODEL;
    __shared__ float buf[16];

    float sq = 0.f, sq2 = 0.f, sk = 0.f, sk2 = 0.f;
    for (int i = threadIdx.x; i < DMODEL; i += 256) {
        float a = qr[i]; sq += a; sq2 += a * a;
        float b = kr[i]; sk += b; sk2 += b * b;
    }
    for (int o = 32; o > 0; o >>= 1) {
        sq += __shfl_down(sq, o); sq2 += __shfl_down(sq2, o);
        sk += __shfl_down(sk, o); sk2 += __shfl_down(sk2, o);
    }
    int wid = threadIdx.x >> 6, lane = threadIdx.x & 63;
    if (lane == 0) { buf[wid] = sq; buf[4 + wid] = sq2; buf[8 + wid] = sk; buf[12 + wid] = sk2; }
    __syncthreads();
    sq = buf[0] + buf[1] + buf[2] + buf[3];
    sq2 = buf[4] + buf[5] + buf[6] + buf[7];
    sk = buf[8] + buf[9] + buf[10] + buf[11];
    sk2 = buf[12] + buf[13] + buf[14] + buf[15];
    float mq = sq * (1.0f / DMODEL);
    float vq = sq2 * (1.0f / DMODEL) - mq * mq;
    float rq = rsqrtf(vq + EPSLN);
    float mk = sk * (1.0f / DMODEL);
    float vk = sk2 * (1.0f / DMODEL) - mk * mk;
    float rk = rsqrtf(vk + EPSLN);

    const float LN10000 = 9.210340371976184f;
    for (int p = threadIdx.x; p < NHEAD * 32; p += 256) {
        int h = p >> 5, j = p & 31;
        int i1 = h * DHEAD + j;
        int i2 = i1 + 32;
        float q1 = (qr[i1] - mq) * rq * qw[i1];
        float q2 = (qr[i2] - mq) * rq * qw[i2];
        float k1 = (kr[i1] - mk) * rk * kw[i1];
        float k2 = (kr[i2] - mk) * rk * kw[i2];
        float inv = __expf(-LN10000 * (float)(2 * j) * (1.0f / DHEAD));
        float ang = (float)l * inv;
        float c, s;
        __sincosf(ang, &s, &c);
        size_t base = ((size_t)h * LSEQ + l) * DHEAD;
        qh[base + j]      = __float2bfloat16(q1 * c - q2 * s);
        qh[base + 32 + j] = __float2bfloat16(q2 * c + q1 * s);
        kh[base + j]      = __float2bfloat16(k1 * c - k2 * s);
        kh[base + 32 + j] = __float2bfloat16(k2 * c + k1 * s);
    }
}

// ---------------------------------------------------------------------------
// Kernel 3b: V transpose -> bf16 vt[H][DH][L] (d-major).
// ---------------------------------------------------------------------------
__global__ __launch_bounds__(256) void v_transpose(const float* __restrict__ qkv,
                                                   __hip_bfloat16* __restrict__ vt) {
    int t = blockIdx.x, h = blockIdx.y;
    int tid = threadIdx.x;
    __shared__ float tile[64][65];
    for (int e = tid; e < 4096; e += 256) {
        int tok = e >> 6, d = e & 63;
        tile[tok][d] = qkv[(size_t)(t * 64 + tok) * D3 + 2 * DMODEL + h * DHEAD + d];
    }
    __syncthreads();
    for (int e = tid; e < 4096; e += 256) {
        int d = e >> 6, tok = e & 63;
        vt[((size_t)h * DHEAD + d) * LSEQ + t * 64 + tok] = __float2bfloat16(tile[tok][d]);
    }
}

// ---------------------------------------------------------------------------
// Kernel 4: MFMA flash attention (unchanged from round 7 except epilogue now
// writes ctx as Dekker-split bf16 hi/lo for the split out-proj GEMM).
// ---------------------------------------------------------------------------
__global__ __launch_bounds__(256) void attn_mfma(const __hip_bfloat16* __restrict__ qh,
                                                 const __hip_bfloat16* __restrict__ kh,
                                                 const __hip_bfloat16* __restrict__ vt,
                                                 const int* __restrict__ seq,
                                                 unsigned short* __restrict__ ctx_hi,
                                                 unsigned short* __restrict__ ctx_lo) {
    int h = blockIdx.y;
    int q0 = blockIdx.x * 64;
    int tid = threadIdx.x;
    int w = tid >> 6, lane = tid & 63;
    int g = lane >> 4, l16 = lane & 15;

    __shared__ __align__(16) unsigned short Klds[64 * 64];      // [tok][d]  swizzled
    __shared__ __align__(16) unsigned short Vlds[64 * 64];      // [d][tok]  swizzled
    __shared__ __align__(16) unsigned short Plds[4][16 * 64];   // per wave [qrow][tok] swizzled
    __shared__ int seq_lds[64];

    int qrow = q0 + w * 16 + l16;
    short8 qfrag[2];
    {
        const short8* qp = (const short8*)(qh + ((size_t)h * LSEQ + qrow) * DHEAD);
        qfrag[0] = qp[g];
        qfrag[1] = qp[4 + g];
    }
    int seq_q[4];
#pragma unroll
    for (int r = 0; r < 4; ++r) seq_q[r] = seq[q0 + w * 16 + g * 4 + r];

    f32x4 O[4] = {};
    float mrow[4], lrow[4];
#pragma unroll
    for (int r = 0; r < 4; ++r) { mrow[r] = -1e30f; lrow[r] = 0.f; }

    for (int t = 0; t < LSEQ / 64; ++t) {
        __syncthreads();
#pragma unroll
        for (int i = 0; i < 2; ++i) {
            int c = 2 * w + i;
            int s = c * 64 + lane;
            int tok = s >> 3, d0 = (s & 7) * 8;
            const __hip_bfloat16* ksrc =
                kh + ((size_t)h * LSEQ + t * 64 + tok) * DHEAD + (d0 ^ ((tok & 7) << 3));
            __builtin_amdgcn_global_load_lds(
                (const __attribute__((address_space(1))) unsigned int*)ksrc,
                (__attribute__((address_space(3))) unsigned int*)&Klds[c * 512],
                16, 0, 0);
            int d = s >> 3, u0 = (s & 7) * 8;
            const __hip_bfloat16* vsrc =
                vt + ((size_t)h * DHEAD + d) * LSEQ + t * 64 + (u0 ^ ((d & 7) << 3));
            __builtin_amdgcn_global_load_lds(
                (const __attribute__((address_space(1))) unsigned int*)vsrc,
                (__attribute__((address_space(3))) unsigned int*)&Vlds[c * 512],
                16, 0, 0);
        }
        if (tid < 64) seq_lds[tid] = seq[t * 64 + tid];
        __syncthreads();

        f32x4 S[4];
#pragma unroll
        for (int nt = 0; nt < 4; ++nt) {
            int tok = nt * 16 + l16;
            short8 b0 = *(const short8*)&Klds[tok * 64 + ((g * 8) ^ ((tok & 7) << 3))];
            short8 b1 = *(const short8*)&Klds[tok * 64 + ((32 + g * 8) ^ ((tok & 7) << 3))];
            f32x4 acc = {0.f, 0.f, 0.f, 0.f};
            acc = __builtin_amdgcn_mfma_f32_16x16x32_bf16(qfrag[0], b0, acc, 0, 0, 0);
            acc = __builtin_amdgcn_mfma_f32_16x16x32_bf16(qfrag[1], b1, acc, 0, 0, 0);
            S[nt] = acc;
        }

        int sk[4];
#pragma unroll
        for (int nt = 0; nt < 4; ++nt) sk[nt] = seq_lds[nt * 16 + l16];

        float p[4][4];
        float tmax[4];
#pragma unroll
        for (int r = 0; r < 4; ++r) tmax[r] = -1e30f;
#pragma unroll
        for (int nt = 0; nt < 4; ++nt)
#pragma unroll
            for (int r = 0; r < 4; ++r) {
                float sv = S[nt][r] * 0.125f + ((sk[nt] == seq_q[r]) ? 1.0f : 0.0f);
                p[nt][r] = sv;
                tmax[r] = fmaxf(tmax[r], sv);
            }
#pragma unroll
        for (int o = 1; o < 16; o <<= 1)
#pragma unroll
            for (int r = 0; r < 4; ++r) tmax[r] = fmaxf(tmax[r], __shfl_xor(tmax[r], o, 64));

        float rsum[4];
#pragma unroll
        for (int r = 0; r < 4; ++r) {
            float mnew = fmaxf(mrow[r], tmax[r]);
            float sc = __expf(mrow[r] - mnew);
            mrow[r] = mnew;
            lrow[r] *= sc;
#pragma unroll
            for (int nt = 0; nt < 4; ++nt) O[nt][r] *= sc;
            float rs = 0.f;
#pragma unroll
            for (int nt = 0; nt < 4; ++nt) {
                float pv = __expf(p[nt][r] - mnew);
                p[nt][r] = pv;
                rs += pv;
            }
            rsum[r] = rs;
        }
#pragma unroll
        for (int o = 1; o < 16; o <<= 1)
#pragma unroll
            for (int r = 0; r < 4; ++r) rsum[r] += __shfl_xor(rsum[r], o, 64);
#pragma unroll
        for (int r = 0; r < 4; ++r) lrow[r] += rsum[r];

        unsigned short* Pw = (unsigned short*)Plds[w];
#pragma unroll
        for (int nt = 0; nt < 4; ++nt)
#pragma unroll
            for (int r = 0; r < 4; ++r) {
                int row = g * 4 + r;
                int col = nt * 16 + l16;
                Pw[row * 64 + (col ^ ((row & 7) << 3))] = f2bf(p[nt][r]);
            }

#pragma unroll
        for (int nt = 0; nt < 4; ++nt) {
            int d = nt * 16 + l16;
            short8 vb0 = *(const short8*)&Vlds[d * 64 + ((g * 8) ^ ((d & 7) << 3))];
            short8 vb1 = *(const short8*)&Vlds[d * 64 + ((32 + g * 8) ^ ((d & 7) << 3))];
            int pr = l16;
            short8 pa0 = *(const short8*)&Pw[pr * 64 + ((g * 8) ^ ((pr & 7) << 3))];
            short8 pa1 = *(const short8*)&Pw[pr * 64 + ((32 + g * 8) ^ ((pr & 7) << 3))];
            O[nt] = __builtin_amdgcn_mfma_f32_16x16x32_bf16(pa0, vb0, O[nt], 0, 0, 0);
            O[nt] = __builtin_amdgcn_mfma_f32_16x16x32_bf16(pa1, vb1, O[nt], 0, 0, 0);
        }
    }

    // ---- epilogue: normalize, Dekker-split, write ctx_hi/lo [L][D] ----
#pragma unroll
    for (int nt = 0; nt < 4; ++nt)
#pragma unroll
        for (int r = 0; r < 4; ++r) {
            int row = g * 4 + r;
            float o = O[nt][r] / lrow[r];
            unsigned short hi = f2bf(o);
            size_t idx = (size_t)(q0 + w * 16 + row) * DMODEL + h * DHEAD + nt * 16 + l16;
            ctx_hi[idx] = hi;
            ctx_lo[idx] = f2bf(o - bf2f(hi));
        }
}

// ---------------------------------------------------------------------------
// Launch
// ---------------------------------------------------------------------------
extern "C" void kernel_launch(void* const* d_in, const int* in_sizes, int n_in,
                              void* d_out, int out_size, void* d_ws, size_t ws_size,
                              hipStream_t stream) {
    const float* x      = (const float*)d_in[0];
    const int*   seq    = (const int*)d_in[2];
    const float* ln_w   = (const float*)d_in[3];
    const float* ln_b   = (const float*)d_in[4];
    const float* w_qkv  = (const float*)d_in[5];
    const float* q_ln_w = (const float*)d_in[6];
    const float* k_ln_w = (const float*)d_in[7];
    const float* w_out  = (const float*)d_in[8];
    float* out = (float*)d_out;

    // Workspace layout (bytes; total 44,040,192 B = identical to round-1 peak)
    char* ws = (char*)d_ws;
    float* qkv            = (float*)ws;                             // 18,874,368 B
    unsigned short* wqT_h = (unsigned short*)(ws + 18874368);       //  3,538,944
    unsigned short* wqT_l = (unsigned short*)(ws + 22413312);       //  3,538,944
    unsigned short* woT_h = (unsigned short*)(ws + 25952256);       //  1,179,648
    unsigned short* woT_l = (unsigned short*)(ws + 27131904);       //  1,179,648
    __hip_bfloat16* qh    = (__hip_bfloat16*)(ws + 28311552);       //  3,145,728
    __hip_bfloat16* kh    = (__hip_bfloat16*)(ws + 31457280);       //  3,145,728
    __hip_bfloat16* vt    = (__hip_bfloat16*)(ws + 34603008);       //  3,145,728
    unsigned short* h_hi  = (unsigned short*)(ws + 37748736);       //  3,145,728
    unsigned short* h_lo  = (unsigned short*)(ws + 40894464);       //  3,145,728
    // h_hi/h_lo dead after qkv GEMM -> reused for ctx_hi/ctx_lo
    unsigned short* ctx_hi = h_hi;
    unsigned short* ctx_lo = h_lo;

    hipLaunchKernelGGL(ln_split_kernel, dim3(LSEQ), dim3(256), 0, stream,
                       x, ln_w, ln_b, h_hi, h_lo);
    hipLaunchKernelGGL(transpose_split, dim3(D3 / 64, DMODEL / 64), dim3(256), 0, stream,
                       w_qkv, wqT_h, wqT_l, DMODEL, D3);
    hipLaunchKernelGGL(transpose_split, dim3(DMODEL / 64, DMODEL / 64), dim3(256), 0, stream,
                       w_out, woT_h, woT_l, DMODEL, DMODEL);
    hipLaunchKernelGGL(gemm_split, dim3(D3 / 128, LSEQ / 128), dim3(256), 0, stream,
                       h_hi, h_lo, wqT_h, wqT_l, qkv, LSEQ, D3, DMODEL);
    hipLaunchKernelGGL(qkln_rope_kernel, dim3(LSEQ), dim3(256), 0, stream,
                       qkv, q_ln_w, k_ln_w, qh, kh);
    hipLaunchKernelGGL(v_transpose, dim3(LSEQ / 64, NHEAD), dim3(256), 0, stream,
                       qkv, vt);
    hipLaunchKernelGGL(attn_mfma, dim3(LSEQ / 64, NHEAD), dim3(256), 0, stream,
                       qh, kh, vt, seq, ctx_hi, ctx_lo);
    hipLaunchKernelGGL(gemm_split, dim3(DMODEL / 128, LSEQ / 128), dim3(256), 0, stream,
                       ctx_hi, ctx_lo, woT_h, woT_l, out, LSEQ, DMODEL, DMODEL);
}

// Round 9
// 147.122 us; speedup vs baseline: 8.0432x; 1.1264x over previous
//
#include <hip/hip_runtime.h>
#include <hip/hip_bf16.h>
#include <math.h>

// Problem constants
#define LSEQ 2048
#define DMODEL 768
#define NHEAD 12
#define DHEAD 64
#define D3 2304
#define EPSLN 1e-5f
#define NSEG 4
#define SEGTILES 8   // 32 KV tiles / NSEG

typedef __attribute__((ext_vector_type(8))) short short8;
typedef __attribute__((ext_vector_type(4))) float f32x4;

static __device__ __forceinline__ unsigned short f2bf(float x) {
    __hip_bfloat16 b = __float2bfloat16(x);
    return *reinterpret_cast<unsigned short*>(&b);
}
static __device__ __forceinline__ float bf2f(unsigned short u) {
    __hip_bfloat16 b = *reinterpret_cast<__hip_bfloat16*>(&u);
    return __bfloat162float(b);
}

// ---------------------------------------------------------------------------
// Kernel 1: LayerNorm + Dekker split -> h_hi, h_lo (bf16). One block per row.
// ---------------------------------------------------------------------------
__global__ __launch_bounds__(256) void ln_split_kernel(const float* __restrict__ x,
                                                       const float* __restrict__ w,
                                                       const float* __restrict__ b,
                                                       unsigned short* __restrict__ hhi,
                                                       unsigned short* __restrict__ hlo) {
    int row = blockIdx.x;
    const float* xr = x + (size_t)row * DMODEL;
    __shared__ float buf[8];

    float s = 0.f, s2 = 0.f;
    for (int i = threadIdx.x; i < DMODEL; i += 256) {
        float v = xr[i];
        s += v; s2 += v * v;
    }
    for (int o = 32; o > 0; o >>= 1) { s += __shfl_down(s, o); s2 += __shfl_down(s2, o); }
    int wid = threadIdx.x >> 6, lane = threadIdx.x & 63;
    if (lane == 0) { buf[wid] = s; buf[4 + wid] = s2; }
    __syncthreads();
    s = buf[0] + buf[1] + buf[2] + buf[3];
    s2 = buf[4] + buf[5] + buf[6] + buf[7];
    float mean = s * (1.0f / DMODEL);
    float var = s2 * (1.0f / DMODEL) - mean * mean;
    float r = rsqrtf(var + EPSLN);
    for (int i = threadIdx.x; i < DMODEL; i += 256) {
        float y = (xr[i] - mean) * r * w[i] + b[i];
        unsigned short hi = f2bf(y);
        hhi[(size_t)row * DMODEL + i] = hi;
        hlo[(size_t)row * DMODEL + i] = f2bf(y - bf2f(hi));
    }
}

// ---------------------------------------------------------------------------
// Kernel 1b: transpose + Dekker split: W[K][N] -> T_hi/T_lo [N][K] (bf16).
// ---------------------------------------------------------------------------
__global__ __launch_bounds__(256) void transpose_split(const float* __restrict__ W,
                                                       unsigned short* __restrict__ Thi,
                                                       unsigned short* __restrict__ Tlo,
                                                       int K, int N) {
    int n0 = blockIdx.x * 64, k0 = blockIdx.y * 64;
    int tid = threadIdx.x;
    __shared__ float tile[64][65];
    for (int e = tid; e < 4096; e += 256) {
        int r = e >> 6, c = e & 63;   // r: k, c: n
        tile[r][c] = W[(size_t)(k0 + r) * N + n0 + c];
    }
    __syncthreads();
    for (int e = tid; e < 4096; e += 256) {
        int r = e >> 6, c = e & 63;   // r: n, c: k
        float v = tile[c][r];
        unsigned short hi = f2bf(v);
        size_t idx = (size_t)(n0 + r) * K + k0 + c;
        Thi[idx] = hi;
        Tlo[idx] = f2bf(v - bf2f(hi));
    }
}

// ---------------------------------------------------------------------------
// Kernel 2: split-bf16 MFMA GEMM (unchanged from round 8).
// ---------------------------------------------------------------------------
__global__ __launch_bounds__(256) void gemm_split(const unsigned short* __restrict__ Ahi,
                                                  const unsigned short* __restrict__ Alo,
                                                  const unsigned short* __restrict__ Bhi,
                                                  const unsigned short* __restrict__ Blo,
                                                  float* __restrict__ C,
                                                  int M, int N, int K) {
    __shared__ __align__(16) unsigned short Ah[128 * 64];
    __shared__ __align__(16) unsigned short Al[128 * 64];
    __shared__ __align__(16) unsigned short Bh[128 * 64];
    __shared__ __align__(16) unsigned short Bl[128 * 64];

    int bx = blockIdx.x, by = blockIdx.y;
    int tid = threadIdx.x;
    int w = tid >> 6, lane = tid & 63;
    int g = lane >> 4, l16 = lane & 15;
    int wm = w >> 1, wn = w & 1;

    f32x4 acc[4][4] = {};

    for (int k0 = 0; k0 < K; k0 += 64) {
        __syncthreads();
#pragma unroll
        for (int c = 0; c < 4; ++c) {
            int slotb = c * 256 + w * 64;
            int slot = slotb + lane;
            int row = slot >> 3;
            int ss = (slot & 7) ^ (row & 7);
            size_t offA = (size_t)(by * 128 + row) * K + k0 + ss * 8;
            size_t offB = (size_t)(bx * 128 + row) * K + k0 + ss * 8;
            __builtin_amdgcn_global_load_lds(
                (const __attribute__((address_space(1))) unsigned int*)(Ahi + offA),
                (__attribute__((address_space(3))) unsigned int*)&Ah[(size_t)slotb * 8], 16, 0, 0);
            __builtin_amdgcn_global_load_lds(
                (const __attribute__((address_space(1))) unsigned int*)(Alo + offA),
                (__attribute__((address_space(3))) unsigned int*)&Al[(size_t)slotb * 8], 16, 0, 0);
            __builtin_amdgcn_global_load_lds(
                (const __attribute__((address_space(1))) unsigned int*)(Bhi + offB),
                (__attribute__((address_space(3))) unsigned int*)&Bh[(size_t)slotb * 8], 16, 0, 0);
            __builtin_amdgcn_global_load_lds(
                (const __attribute__((address_space(1))) unsigned int*)(Blo + offB),
                (__attribute__((address_space(3))) unsigned int*)&Bl[(size_t)slotb * 8], 16, 0, 0);
        }
        __syncthreads();

#pragma unroll
        for (int kk = 0; kk < 2; ++kk) {
            short8 a_h[4], a_l[4], b_h[4], b_l[4];
#pragma unroll
            for (int i = 0; i < 4; ++i) {
                int row = wm * 64 + i * 16 + l16;
                int s = (kk * 4 + g) ^ (row & 7);
                a_h[i] = *(const short8*)&Ah[row * 64 + s * 8];
                a_l[i] = *(const short8*)&Al[row * 64 + s * 8];
            }
#pragma unroll
            for (int j = 0; j < 4; ++j) {
                int row = wn * 64 + j * 16 + l16;
                int s = (kk * 4 + g) ^ (row & 7);
                b_h[j] = *(const short8*)&Bh[row * 64 + s * 8];
                b_l[j] = *(const short8*)&Bl[row * 64 + s * 8];
            }
#pragma unroll
            for (int i = 0; i < 4; ++i)
#pragma unroll
                for (int j = 0; j < 4; ++j) {
                    acc[i][j] = __builtin_amdgcn_mfma_f32_16x16x32_bf16(a_h[i], b_h[j], acc[i][j], 0, 0, 0);
                    acc[i][j] = __builtin_amdgcn_mfma_f32_16x16x32_bf16(a_h[i], b_l[j], acc[i][j], 0, 0, 0);
                    acc[i][j] = __builtin_amdgcn_mfma_f32_16x16x32_bf16(a_l[i], b_h[j], acc[i][j], 0, 0, 0);
                }
        }
    }

#pragma unroll
    for (int i = 0; i < 4; ++i)
#pragma unroll
        for (int j = 0; j < 4; ++j)
#pragma unroll
            for (int r = 0; r < 4; ++r) {
                int m = by * 128 + wm * 64 + i * 16 + g * 4 + r;
                int n = bx * 128 + wn * 64 + j * 16 + l16;
                C[(size_t)m * N + n] = acc[i][j][r];
            }
}

// ---------------------------------------------------------------------------
// Kernel 3: qk-LayerNorm + RoPE -> bf16 q,k in [H][L][DH]. One block per token.
// ---------------------------------------------------------------------------
__global__ __launch_bounds__(256) void qkln_rope_kernel(const float* __restrict__ qkv,
                                                        const float* __restrict__ qw,
                                                        const float* __restrict__ kw,
                                                        __hip_bfloat16* __restrict__ qh,
                                                        __hip_bfloat16* __restrict__ kh) {
    int l = blockIdx.x;
    const float* qr = qkv + (size_t)l * D3;
    const float* kr = qr + DMODEL;
    __shared__ float buf[16];

    float sq = 0.f, sq2 = 0.f, sk = 0.f, sk2 = 0.f;
    for (int i = threadIdx.x; i < DMODEL; i += 256) {
        float a = qr[i]; sq += a; sq2 += a * a;
        float b = kr[i]; sk += b; sk2 += b * b;
    }
    for (int o = 32; o > 0; o >>= 1) {
        sq += __shfl_down(sq, o); sq2 += __shfl_down(sq2, o);
        sk += __shfl_down(sk, o); sk2 += __shfl_down(sk2, o);
    }
    int wid = threadIdx.x >> 6, lane = threadIdx.x & 63;
    if (lane == 0) { buf[wid] = sq; buf[4 + wid] = sq2; buf[8 + wid] = sk; buf[12 + wid] = sk2; }
    __syncthreads();
    sq = buf[0] + buf[1] + buf[2] + buf[3];
    sq2 = buf[4] + buf[5] + buf[6] + buf[7];
    sk = buf[8] + buf[9] + buf[10] + buf[11];
    sk2 = buf[12] + buf[13] + buf[14] + buf[15];
    float mq = sq * (1.0f / DMODEL);
    float vq = sq2 * (1.0f / DMODEL) - mq * mq;
    float rq = rsqrtf(vq + EPSLN);
    float mk = sk * (1.0f / DMODEL);
    float vk = sk2 * (1.0f / DMODEL) - mk * mk;
    float rk = rsqrtf(vk + EPSLN);

    const float LN10000 = 9.210340371976184f;
    for (int p = threadIdx.x; p < NHEAD * 32; p += 256) {
        int h = p >> 5, j = p & 31;
        int i1 = h * DHEAD + j;
        int i2 = i1 + 32;
        float q1 = (qr[i1] - mq) * rq * qw[i1];
        float q2 = (qr[i2] - mq) * rq * qw[i2];
        float k1 = (kr[i1] - mk) * rk * kw[i1];
        float k2 = (kr[i2] - mk) * rk * kw[i2];
        float inv = __expf(-LN10000 * (float)(2 * j) * (1.0f / DHEAD));
        float ang = (float)l * inv;
        float c, s;
        __sincosf(ang, &s, &c);
        size_t base = ((size_t)h * LSEQ + l) * DHEAD;
        qh[base + j]      = __float2bfloat16(q1 * c - q2 * s);
        qh[base + 32 + j] = __float2bfloat16(q2 * c + q1 * s);
        kh[base + j]      = __float2bfloat16(k1 * c - k2 * s);
        kh[base + 32 + j] = __float2bfloat16(k2 * c + k1 * s);
    }
}

// ---------------------------------------------------------------------------
// Kernel 3b: V transpose -> bf16 vt[H][DH][L] (d-major).
// ---------------------------------------------------------------------------
__global__ __launch_bounds__(256) void v_transpose(const float* __restrict__ qkv,
                                                   __hip_bfloat16* __restrict__ vt) {
    int t = blockIdx.x, h = blockIdx.y;
    int tid = threadIdx.x;
    __shared__ float tile[64][65];
    for (int e = tid; e < 4096; e += 256) {
        int tok = e >> 6, d = e & 63;
        tile[tok][d] = qkv[(size_t)(t * 64 + tok) * D3 + 2 * DMODEL + h * DHEAD + d];
    }
    __syncthreads();
    for (int e = tid; e < 4096; e += 256) {
        int d = e >> 6, tok = e & 63;
        vt[((size_t)h * DHEAD + d) * LSEQ + t * 64 + tok] = __float2bfloat16(tile[tok][d]);
    }
}

// ---------------------------------------------------------------------------
// Kernel 4: MFMA flash attention. PARTIAL=true: grid (32,12,NSEG), each block
// handles SEGTILES KV tiles and writes unnormalized partial O + (m,l).
// PARTIAL=false: single-pass (round-8 behavior), writes Dekker-split ctx.
// ---------------------------------------------------------------------------
template <bool PARTIAL>
__global__ __launch_bounds__(256) void attn_mfma(const __hip_bfloat16* __restrict__ qh,
                                                 const __hip_bfloat16* __restrict__ kh,
                                                 const __hip_bfloat16* __restrict__ vt,
                                                 const int* __restrict__ seq,
                                                 unsigned short* __restrict__ ctx_hi,
                                                 unsigned short* __restrict__ ctx_lo,
                                                 float* __restrict__ Opart,
                                                 float* __restrict__ Mpart,
                                                 float* __restrict__ Lpart) {
    int h = blockIdx.y;
    int q0 = blockIdx.x * 64;
    int sg = PARTIAL ? blockIdx.z : 0;
    int tid = threadIdx.x;
    int w = tid >> 6, lane = tid & 63;
    int g = lane >> 4, l16 = lane & 15;

    __shared__ __align__(16) unsigned short Klds[64 * 64];
    __shared__ __align__(16) unsigned short Vlds[64 * 64];
    __shared__ __align__(16) unsigned short Plds[4][16 * 64];
    __shared__ int seq_lds[64];

    int qrow = q0 + w * 16 + l16;
    short8 qfrag[2];
    {
        const short8* qp = (const short8*)(qh + ((size_t)h * LSEQ + qrow) * DHEAD);
        qfrag[0] = qp[g];
        qfrag[1] = qp[4 + g];
    }
    int seq_q[4];
#pragma unroll
    for (int r = 0; r < 4; ++r) seq_q[r] = seq[q0 + w * 16 + g * 4 + r];

    f32x4 O[4] = {};
    float mrow[4], lrow[4];
#pragma unroll
    for (int r = 0; r < 4; ++r) { mrow[r] = -1e30f; lrow[r] = 0.f; }

    int t0 = PARTIAL ? sg * SEGTILES : 0;
    int t1 = PARTIAL ? t0 + SEGTILES : LSEQ / 64;

    for (int t = t0; t < t1; ++t) {
        __syncthreads();
#pragma unroll
        for (int i = 0; i < 2; ++i) {
            int c = 2 * w + i;
            int s = c * 64 + lane;
            int tok = s >> 3, d0 = (s & 7) * 8;
            const __hip_bfloat16* ksrc =
                kh + ((size_t)h * LSEQ + t * 64 + tok) * DHEAD + (d0 ^ ((tok & 7) << 3));
            __builtin_amdgcn_global_load_lds(
                (const __attribute__((address_space(1))) unsigned int*)ksrc,
                (__attribute__((address_space(3))) unsigned int*)&Klds[c * 512],
                16, 0, 0);
            int d = s >> 3, u0 = (s & 7) * 8;
            const __hip_bfloat16* vsrc =
                vt + ((size_t)h * DHEAD + d) * LSEQ + t * 64 + (u0 ^ ((d & 7) << 3));
            __builtin_amdgcn_global_load_lds(
                (const __attribute__((address_space(1))) unsigned int*)vsrc,
                (__attribute__((address_space(3))) unsigned int*)&Vlds[c * 512],
                16, 0, 0);
        }
        if (tid < 64) seq_lds[tid] = seq[t * 64 + tid];
        __syncthreads();

        f32x4 S[4];
#pragma unroll
        for (int nt = 0; nt < 4; ++nt) {
            int tok = nt * 16 + l16;
            short8 b0 = *(const short8*)&Klds[tok * 64 + ((g * 8) ^ ((tok & 7) << 3))];
            short8 b1 = *(const short8*)&Klds[tok * 64 + ((32 + g * 8) ^ ((tok & 7) << 3))];
            f32x4 acc = {0.f, 0.f, 0.f, 0.f};
            acc = __builtin_amdgcn_mfma_f32_16x16x32_bf16(qfrag[0], b0, acc, 0, 0, 0);
            acc = __builtin_amdgcn_mfma_f32_16x16x32_bf16(qfrag[1], b1, acc, 0, 0, 0);
            S[nt] = acc;
        }

        int sk[4];
#pragma unroll
        for (int nt = 0; nt < 4; ++nt) sk[nt] = seq_lds[nt * 16 + l16];

        float p[4][4];
        float tmax[4];
#pragma unroll
        for (int r = 0; r < 4; ++r) tmax[r] = -1e30f;
#pragma unroll
        for (int nt = 0; nt < 4; ++nt)
#pragma unroll
            for (int r = 0; r < 4; ++r) {
                float sv = S[nt][r] * 0.125f + ((sk[nt] == seq_q[r]) ? 1.0f : 0.0f);
                p[nt][r] = sv;
                tmax[r] = fmaxf(tmax[r], sv);
            }
#pragma unroll
        for (int o = 1; o < 16; o <<= 1)
#pragma unroll
            for (int r = 0; r < 4; ++r) tmax[r] = fmaxf(tmax[r], __shfl_xor(tmax[r], o, 64));

        float rsum[4];
#pragma unroll
        for (int r = 0; r < 4; ++r) {
            float mnew = fmaxf(mrow[r], tmax[r]);
            float sc = __expf(mrow[r] - mnew);
            mrow[r] = mnew;
            lrow[r] *= sc;
#pragma unroll
            for (int nt = 0; nt < 4; ++nt) O[nt][r] *= sc;
            float rs = 0.f;
#pragma unroll
            for (int nt = 0; nt < 4; ++nt) {
                float pv = __expf(p[nt][r] - mnew);
                p[nt][r] = pv;
                rs += pv;
            }
            rsum[r] = rs;
        }
#pragma unroll
        for (int o = 1; o < 16; o <<= 1)
#pragma unroll
            for (int r = 0; r < 4; ++r) rsum[r] += __shfl_xor(rsum[r], o, 64);
#pragma unroll
        for (int r = 0; r < 4; ++r) lrow[r] += rsum[r];

        unsigned short* Pw = (unsigned short*)Plds[w];
#pragma unroll
        for (int nt = 0; nt < 4; ++nt)
#pragma unroll
            for (int r = 0; r < 4; ++r) {
                int row = g * 4 + r;
                int col = nt * 16 + l16;
                Pw[row * 64 + (col ^ ((row & 7) << 3))] = f2bf(p[nt][r]);
            }

#pragma unroll
        for (int nt = 0; nt < 4; ++nt) {
            int d = nt * 16 + l16;
            short8 vb0 = *(const short8*)&Vlds[d * 64 + ((g * 8) ^ ((d & 7) << 3))];
            short8 vb1 = *(const short8*)&Vlds[d * 64 + ((32 + g * 8) ^ ((d & 7) << 3))];
            int pr = l16;
            short8 pa0 = *(const short8*)&Pw[pr * 64 + ((g * 8) ^ ((pr & 7) << 3))];
            short8 pa1 = *(const short8*)&Pw[pr * 64 + ((32 + g * 8) ^ ((pr & 7) << 3))];
            O[nt] = __builtin_amdgcn_mfma_f32_16x16x32_bf16(pa0, vb0, O[nt], 0, 0, 0);
            O[nt] = __builtin_amdgcn_mfma_f32_16x16x32_bf16(pa1, vb1, O[nt], 0, 0, 0);
        }
    }

    if (PARTIAL) {
        // unnormalized partial O + per-row m,l
#pragma unroll
        for (int nt = 0; nt < 4; ++nt)
#pragma unroll
            for (int r = 0; r < 4; ++r) {
                int row = g * 4 + r;
                Opart[((size_t)sg * LSEQ + q0 + w * 16 + row) * DMODEL + h * DHEAD + nt * 16 + l16] =
                    O[nt][r];
            }
        if (l16 == 0) {
#pragma unroll
            for (int r = 0; r < 4; ++r) {
                int q = q0 + w * 16 + g * 4 + r;
                Mpart[((size_t)sg * NHEAD + h) * LSEQ + q] = mrow[r];
                Lpart[((size_t)sg * NHEAD + h) * LSEQ + q] = lrow[r];
            }
        }
    } else {
#pragma unroll
        for (int nt = 0; nt < 4; ++nt)
#pragma unroll
            for (int r = 0; r < 4; ++r) {
                int row = g * 4 + r;
                float o = O[nt][r] / lrow[r];
                unsigned short hi = f2bf(o);
                size_t idx = (size_t)(q0 + w * 16 + row) * DMODEL + h * DHEAD + nt * 16 + l16;
                ctx_hi[idx] = hi;
                ctx_lo[idx] = f2bf(o - bf2f(hi));
            }
    }
}

// ---------------------------------------------------------------------------
// Kernel 4b: combine NSEG partials -> Dekker-split ctx. One thread per (q,c).
// ---------------------------------------------------------------------------
__global__ __launch_bounds__(256) void attn_combine(const float* __restrict__ Opart,
                                                    const float* __restrict__ Mpart,
                                                    const float* __restrict__ Lpart,
                                                    unsigned short* __restrict__ ctx_hi,
                                                    unsigned short* __restrict__ ctx_lo) {
    int idx = blockIdx.x * 256 + threadIdx.x;   // < LSEQ*DMODEL
    int q = idx / DMODEL;
    int c = idx - q * DMODEL;
    int h = c >> 6;

    float ms[NSEG];
    float m = -1e30f;
#pragma unroll
    for (int s = 0; s < NSEG; ++s) {
        ms[s] = Mpart[((size_t)s * NHEAD + h) * LSEQ + q];
        m = fmaxf(m, ms[s]);
    }
    float denom = 0.f, o = 0.f;
#pragma unroll
    for (int s = 0; s < NSEG; ++s) {
        float e = __expf(ms[s] - m);
        denom += Lpart[((size_t)s * NHEAD + h) * LSEQ + q] * e;
        o += Opart[((size_t)s * LSEQ + q) * DMODEL + c] * e;
    }
    float res = o / denom;
    unsigned short hi = f2bf(res);
    ctx_hi[idx] = hi;
    ctx_lo[idx] = f2bf(res - bf2f(hi));
}

// ---------------------------------------------------------------------------
// Launch
// ---------------------------------------------------------------------------
extern "C" void kernel_launch(void* const* d_in, const int* in_sizes, int n_in,
                              void* d_out, int out_size, void* d_ws, size_t ws_size,
                              hipStream_t stream) {
    const float* x      = (const float*)d_in[0];
    const int*   seq    = (const int*)d_in[2];
    const float* ln_w   = (const float*)d_in[3];
    const float* ln_b   = (const float*)d_in[4];
    const float* w_qkv  = (const float*)d_in[5];
    const float* q_ln_w = (const float*)d_in[6];
    const float* k_ln_w = (const float*)d_in[7];
    const float* w_out  = (const float*)d_in[8];
    float* out = (float*)d_out;

    // Workspace layout (bytes). Base block = 44,040,192 (round-8 layout).
    char* ws = (char*)d_ws;
    float* qkv            = (float*)ws;                             // 18,874,368
    unsigned short* wqT_h = (unsigned short*)(ws + 18874368);       //  3,538,944
    unsigned short* wqT_l = (unsigned short*)(ws + 22413312);       //  3,538,944
    unsigned short* woT_h = (unsigned short*)(ws + 25952256);       //  1,179,648
    unsigned short* woT_l = (unsigned short*)(ws + 27131904);       //  1,179,648
    __hip_bfloat16* qh    = (__hip_bfloat16*)(ws + 28311552);       //  3,145,728
    __hip_bfloat16* kh    = (__hip_bfloat16*)(ws + 31457280);       //  3,145,728
    __hip_bfloat16* vt    = (__hip_bfloat16*)(ws + 34603008);       //  3,145,728
    unsigned short* h_hi  = (unsigned short*)(ws + 37748736);       //  3,145,728
    unsigned short* h_lo  = (unsigned short*)(ws + 40894464);       //  3,145,728
    unsigned short* ctx_hi = h_hi;   // reuse after qkv GEMM
    unsigned short* ctx_lo = h_lo;

    // KV-split partials (only if workspace allows)
    const size_t BASE = 44040192;
    float* Opart = (float*)(ws + BASE);                             // 25,165,824
    float* Mpart = (float*)(ws + BASE + 25165824);                  //    393,216
    float* Lpart = (float*)(ws + BASE + 25559040);                  //    393,216
    const size_t NEED = BASE + 25952256;
    const bool use_split = (ws_size >= NEED);

    hipLaunchKernelGGL(ln_split_kernel, dim3(LSEQ), dim3(256), 0, stream,
                       x, ln_w, ln_b, h_hi, h_lo);
    hipLaunchKernelGGL(transpose_split, dim3(D3 / 64, DMODEL / 64), dim3(256), 0, stream,
                       w_qkv, wqT_h, wqT_l, DMODEL, D3);
    hipLaunchKernelGGL(transpose_split, dim3(DMODEL / 64, DMODEL / 64), dim3(256), 0, stream,
                       w_out, woT_h, woT_l, DMODEL, DMODEL);
    hipLaunchKernelGGL(gemm_split, dim3(D3 / 128, LSEQ / 128), dim3(256), 0, stream,
                       h_hi, h_lo, wqT_h, wqT_l, qkv, LSEQ, D3, DMODEL);
    hipLaunchKernelGGL(qkln_rope_kernel, dim3(LSEQ), dim3(256), 0, stream,
                       qkv, q_ln_w, k_ln_w, qh, kh);
    hipLaunchKernelGGL(v_transpose, dim3(LSEQ / 64, NHEAD), dim3(256), 0, stream,
                       qkv, vt);
    if (use_split) {
        hipLaunchKernelGGL((attn_mfma<true>), dim3(LSEQ / 64, NHEAD, NSEG), dim3(256), 0, stream,
                           qh, kh, vt, seq, ctx_hi, ctx_lo, Opart, Mpart, Lpart);
        hipLaunchKernelGGL(attn_combine, dim3(LSEQ * DMODEL / 256), dim3(256), 0, stream,
                           Opart, Mpart, Lpart, ctx_hi, ctx_lo);
    } else {
        hipLaunchKernelGGL((attn_mfma<false>), dim3(LSEQ / 64, NHEAD), dim3(256), 0, stream,
                           qh, kh, vt, seq, ctx_hi, ctx_lo, Opart, Mpart, Lpart);
    }
    hipLaunchKernelGGL(gemm_split, dim3(DMODEL / 128, LSEQ / 128), dim3(256), 0, stream,
                       ctx_hi, ctx_lo, woT_h, woT_l, out, LSEQ, DMODEL, DMODEL);
}